// Round 6
// baseline (467.879 us; speedup 1.0000x reference)
//
#include <hip/hip_runtime.h>
#include <math.h>

#define PI_D 3.14159265358979323846264338327950288

#define NPIX 128
#define NFFT 512
#define BATCH 64
#define EXSZ 512          // per-wave exchange region, float2 (XOR layout, no pad)
#define TSTR 130          // passBC staging tile column stride (float2)

__device__ __forceinline__ float2 cmulf(float2 a, float2 b) {
    return make_float2(a.x*b.x - a.y*b.y, a.x*b.y + a.y*b.x);
}
__device__ __forceinline__ float2 cadd(float2 a, float2 b) {
    return make_float2(a.x + b.x, a.y + b.y);
}
__device__ __forceinline__ float2 csub(float2 a, float2 b) {
    return make_float2(a.x - b.x, a.y - b.y);
}

// Compiler-only reorder barrier. Intra-wave LDS RAW/WAR needs no s_waitcnt:
// DS ops from one wave execute in order in the DS pipe; the compiler inserts
// fine-grained lgkmcnt(N) before VALU use of loaded data automatically.
#define CBAR() __asm__ volatile("" ::: "memory")

// conflict-free exchange address maps (bijective mod 16 per 16-lane group)
__device__ __forceinline__ int ex1w(int k, int l)           { return 64*k  + (l ^ (2*k)); }
__device__ __forceinline__ int ex1r(int k, int k2, int hi)  { return 64*k2 + ((hi + 8*k) ^ (2*k2)); }
__device__ __forceinline__ int ex2w(int k, int l)           { return 64*k  + (l ^ (8*k)); }
__device__ __forceinline__ int ex2r(int k, int k2, int hi)  { return 64*hi + ((k2 + 8*k) ^ (8*hi)); }

// ---------------------------------------------------------------------------
// in-register 8-point DFT. SGN=-1 forward; SGN=+1 unnormalized inverse.
// ---------------------------------------------------------------------------
template<int SGN>
__device__ __forceinline__ void dft8(float2* x)
{
    const float C = 0.70710678118654752440f;
    float2 t0 = cadd(x[0], x[4]), t4 = csub(x[0], x[4]);
    float2 t1 = cadd(x[1], x[5]), t5 = csub(x[1], x[5]);
    float2 t2 = cadd(x[2], x[6]), t6 = csub(x[2], x[6]);
    float2 t3 = cadd(x[3], x[7]), t7 = csub(x[3], x[7]);
    float2 u5 = make_float2(C*(t5.x - SGN*t5.y), C*(t5.y + SGN*t5.x));
    float2 u6 = make_float2((float)(-SGN)*t6.y, (float)SGN*t6.x);
    float2 u7 = make_float2(-C*(t7.x + SGN*t7.y), C*(SGN*t7.x - t7.y));
    float2 s0 = cadd(t0, t2), s2 = csub(t0, t2);
    float2 s1 = cadd(t1, t3), d13 = csub(t1, t3);
    float2 s3 = make_float2((float)(-SGN)*d13.y, (float)SGN*d13.x);
    x[0] = cadd(s0, s1); x[4] = csub(s0, s1);
    x[2] = cadd(s2, s3); x[6] = csub(s2, s3);
    float2 s4 = cadd(t4, u6), s6 = csub(t4, u6);
    float2 s5 = cadd(u5, u7), d57 = csub(u5, u7);
    float2 s7 = make_float2((float)(-SGN)*d57.y, (float)SGN*d57.x);
    x[1] = cadd(s4, s5); x[5] = csub(s4, s5);
    x[3] = cadd(s6, s7); x[7] = csub(s6, s7);
}

// apply x[k] *= base^k for k=1..7 (6-cmul chain, low VGPR)
__device__ __forceinline__ void twpow(float2* x, float2 base)
{
    float2 w = base;
#pragma unroll
    for (int k = 1; k < 8; ++k) {
        x[k] = cmulf(x[k], w);
        w = cmulf(w, base);
    }
}

// per-lane twiddle bases (4 VGPRs total), positive angle; conj at callsite.
__device__ __forceinline__ void make_bases(int l, float2* b1, float2* b2)
{
    float s1, c1, s2, c2;
    __sincosf(0.012271846303085129838f * (float)l,        &s1, &c1); // 2pi/512
    __sincosf(0.098174770424681038701f * (float)(l >> 3), &s2, &c2); // 2pi/64
    *b1 = make_float2(c1, s1);
    *b2 = make_float2(c2, s2);
}

// ---------------------------------------------------------------------------
// 512-point FFT, one wave, 8 complex/lane, radix-8 x3, natural order both ends
// bases passed with FORWARD sign already applied (conj for inverse at callsite)
// ---------------------------------------------------------------------------
__device__ __forceinline__ void fwd512(float2* x, float2* ex, int l,
                                       float2 b1, float2 b2)
{
    const int k2 = l & 7, hi = l >> 3;
    dft8<-1>(x);
    twpow(x, b1);
    CBAR();
#pragma unroll
    for (int k = 0; k < 8; ++k) ex[ex1w(k, l)] = x[k];
    CBAR();
#pragma unroll
    for (int k = 0; k < 8; ++k) x[k] = ex[ex1r(k, k2, hi)];
    dft8<-1>(x);
    twpow(x, b2);
    CBAR();
#pragma unroll
    for (int k = 0; k < 8; ++k) ex[ex2w(k, l)] = x[k];
    CBAR();
#pragma unroll
    for (int k = 0; k < 8; ++k) x[k] = ex[ex2r(k, k2, hi)];
    dft8<-1>(x);
}

__device__ __forceinline__ void inv512(float2* x, float2* ex, int l,
                                       float2 b1, float2 b2)
{
    const int k2 = l & 7, hi = l >> 3;
    dft8<1>(x);
    CBAR();
#pragma unroll
    for (int k = 0; k < 8; ++k) ex[ex2r(k, k2, hi)] = x[k];
    CBAR();
#pragma unroll
    for (int k = 0; k < 8; ++k) x[k] = ex[ex2w(k, l)];
    twpow(x, b2);
    dft8<1>(x);
    CBAR();
#pragma unroll
    for (int k = 0; k < 8; ++k) ex[ex1r(k, k2, hi)] = x[k];
    CBAR();
#pragma unroll
    for (int k = 0; k < 8; ++k) x[k] = ex[ex1w(k, l)];
    twpow(x, b1);
    dft8<1>(x);
}

// ---------------------------------------------------------------------------
// setup: H built in double precision via Stockham ping-pong (one-time cost)
// ---------------------------------------------------------------------------
__device__ __forceinline__ int fft512d(double2 (*b)[NFFT], int t, double isign, int cur)
{
    for (int st = 0; st < 9; ++st) {
        const int s = 1 << st;
        const int p = t >> st;
        const int q = t & (s - 1);
        const int m = 256 >> st;
        const double2 a = b[cur][q + s*p];
        const double2 c = b[cur][q + s*(p + m)];
        double sw, cw;
        sincos(isign * (-PI_D/256.0) * (double)(p << st), &sw, &cw);
        const double2 dif = make_double2(a.x - c.x, a.y - c.y);
        b[cur^1][q + 2*s*p]     = make_double2(a.x + c.x, a.y + c.y);
        b[cur^1][q + 2*s*p + s] = make_double2(dif.x*cw - dif.y*sw,
                                               dif.x*sw + dif.y*cw);
        cur ^= 1;
        __syncthreads();
    }
    return cur;
}

__global__ __launch_bounds__(256) void k_build_w(double2* __restrict__ Wd)
{
    const double WLEN = 5.32e-07, PIX = 1.0e-4, DIST = 0.005;
    int idx = blockIdx.x*blockDim.x + threadIdx.x;   // 512*512 total
    int i = idx >> 9, j = idx & 511;
    double2 v = make_double2(0.0, 0.0);
    if (i < 257 && j < 257) {
        double cx = (double)(128 - i) * PIX;
        double cy = (double)(128 - j) * PIX;
        double r2 = cx*cx + cy*cy + DIST*DIST;
        double r  = sqrt(r2);
        double sc = PIX*PIX*DIST / r2;
        double re_a = 1.0/(2.0*PI_D*r);
        double im_a = -1.0/WLEN;
        double sp, cp;
        sincos(2.0*PI_D*r/WLEN, &sp, &cp);
        v.x = sc*(re_a*cp - im_a*sp);
        v.y = sc*(re_a*sp + im_a*cp);
    }
    Wd[idx] = v;
}

__global__ __launch_bounds__(256) void k_dfft_row(const double2* __restrict__ in,
                                                  double2* __restrict__ out)
{
    __shared__ double2 b[2][NFFT];
    int row = blockIdx.x, t = threadIdx.x;
    b[0][t]       = in[row*NFFT + t];
    b[0][t + 256] = in[row*NFFT + t + 256];
    __syncthreads();
    int cur = fft512d(b, t, 1.0, 0);
    out[row*NFFT + t]       = b[cur][t];
    out[row*NFFT + t + 256] = b[cur][t + 256];
}

// column FFT; Ht[kx*512 + ky] natural order, 1/512^2 folded in.
__global__ __launch_bounds__(256) void k_dfft_col_H(const double2* __restrict__ in,
                                                    float2* __restrict__ Ht)
{
    __shared__ double2 b[2][NFFT];
    int col = blockIdx.x, t = threadIdx.x;
    b[0][t]       = in[t*NFFT + col];
    b[0][t + 256] = in[(t + 256)*NFFT + col];
    __syncthreads();
    int cur = fft512d(b, t, 1.0, 0);
    const double scale = 1.0/(512.0*512.0);
    Ht[col*NFFT + t]       = make_float2((float)(b[cur][t].x*scale),
                                         (float)(b[cur][t].y*scale));
    Ht[col*NFFT + t + 256] = make_float2((float)(b[cur][t+256].x*scale),
                                         (float)(b[cur][t+256].y*scale));
}

// ---------------------------------------------------------------------------
// pass A0: init + first row FFT. block 256 = 4 waves = 4 rows, no barriers.
// ---------------------------------------------------------------------------
__global__ __launch_bounds__(256) void k_passA0(const float* __restrict__ x,
                                                float2* __restrict__ Abuf,
                                                float2* __restrict__ outc,
                                                float*  __restrict__ outr)
{
    __shared__ float2 ex_all[4*EXSZ];
    const int w = threadIdx.x >> 6, l = threadIdx.x & 63;
    const int row = blockIdx.x*4 + w, img = blockIdx.y;
    float2* ex = ex_all + w*EXSZ;
    float2 b1, b2;
    make_bases(l, &b1, &b2);

    const float* xr = x + (size_t)(img*NPIX + row)*NPIX;
    float2 v0 = make_float2(xr[l],      0.f);
    float2 v1 = make_float2(xr[l + 64], 0.f);
    size_t o = (size_t)(img*NPIX + row)*NPIX;
    if (outc) { outc[o + l] = v0; outc[o + 64 + l] = v1; }
    else      { outr[o + l] = v0.x; outr[o + 64 + l] = v1.x; }

    float2 X[8];
    X[0] = v0; X[1] = v1;
#pragma unroll
    for (int k = 2; k < 8; ++k) X[k] = make_float2(0.f, 0.f);
    fwd512(X, ex, l, make_float2(b1.x, -b1.y), make_float2(b2.x, -b2.y));
    float2* arow = Abuf + (size_t)(img*NPIX + row)*NFFT;
#pragma unroll
    for (int d = 0; d < 8; ++d) arow[l + 64*d] = X[d];
}

// ---------------------------------------------------------------------------
// pass BC: 8 columns/block (512 thr = 8 waves, 1 col each). Staging tile T
// ALIASES the exchange region (disjoint lifetimes, separated by barriers):
// LDS = 32 KB -> 4 blocks/CU.
// ---------------------------------------------------------------------------
__global__ __launch_bounds__(512) void k_passBC(float2* __restrict__ Abuf,
                                                const float2* __restrict__ Ht)
{
    __shared__ float2 ex_all[8*EXSZ];   // 32768 B: exchange + aliased staging
    float2* T = ex_all;                 // staging tile: 8*TSTR = 1040 slots
    const int t = threadIdx.x;
    const int w = t >> 6, l = t & 63;
    const int img = blockIdx.x, c0 = blockIdx.y*8;
    float2* base = Abuf + (size_t)img*NPIX*NFFT;
    float2 b1, b2;
    make_bases(l, &b1, &b2);

    // coalesced tile load: (128 rows x 8 cols)
#pragma unroll
    for (int i = 0; i < 2; ++i) {
        int idx = t + 512*i;
        int cc = idx & 7, r = idx >> 3;
        T[cc*TSTR + r] = base[r*NFFT + c0 + cc];
    }
    __syncthreads();

    float2* ex = ex_all + w*EXSZ;
    float2 X[8];
    X[0] = T[w*TSTR + l];
    X[1] = T[w*TSTR + l + 64];
#pragma unroll
    for (int k = 2; k < 8; ++k) X[k] = make_float2(0.f, 0.f);
    __syncthreads();   // all waves read T before exchanges overwrite it

    fwd512(X, ex, l, make_float2(b1.x, -b1.y), make_float2(b2.x, -b2.y));
    const float2* Hrow = Ht + (size_t)(c0 + w)*NFFT;
#pragma unroll
    for (int d = 0; d < 8; ++d) X[d] = cmulf(X[d], Hrow[l + 64*d]);
    inv512(X, ex, l, b1, b2);

    __syncthreads();   // all waves done with exchange regions
    // keep spatial rows 128..255 (regs 2,3)
    T[w*TSTR + l]      = X[2];
    T[w*TSTR + l + 64] = X[3];
    __syncthreads();

#pragma unroll
    for (int i = 0; i < 2; ++i) {
        int idx = t + 512*i;
        int cc = idx & 7, r = idx >> 3;
        base[r*NFFT + c0 + cc] = T[cc*TSTR + r];
    }
}

// ---------------------------------------------------------------------------
// pass DA: row IFFT + crop + mask + output, then forward row FFT. No barriers.
// ---------------------------------------------------------------------------
__global__ __launch_bounds__(256) void k_passDA(float2* __restrict__ Abuf,
                                                const float* __restrict__ phases,
                                                float2* __restrict__ outc,
                                                float*  __restrict__ outr,
                                                int layer)
{
    __shared__ float2 ex_all[4*EXSZ];
    const int w = threadIdx.x >> 6, l = threadIdx.x & 63;
    const int row = blockIdx.x*4 + w, img = blockIdx.y;
    float2* ex = ex_all + w*EXSZ;
    float2 b1, b2;
    make_bases(l, &b1, &b2);

    float2* arow = Abuf + (size_t)(img*NPIX + row)*NFFT;
    float2 X[8];
#pragma unroll
    for (int d = 0; d < 8; ++d) X[d] = arow[l + 64*d];
    inv512(X, ex, l, b1, b2);

    // crop cols 128..255 -> j = l (reg2), j = 64+l (reg3); apply mask
    const float* ph = phases + layer*4096 + (row >> 1)*64;
    float p0 = ph[(l >> 1)];
    float p1 = ph[32 + (l >> 1)];
    float cp0 = 6.2831853071795864769f * (1.f/(1.f + __expf(-p0)));
    float cp1 = 6.2831853071795864769f * (1.f/(1.f + __expf(-p1)));
    float s0, c0s, s1, c1s;
    __sincosf(cp0, &s0, &c0s);
    __sincosf(cp1, &s1, &c1s);
    float2 v0 = cmulf(X[2], make_float2(c0s, s0));
    float2 v1 = cmulf(X[3], make_float2(c1s, s1));

    size_t o = (size_t)(img*NPIX + row)*NPIX;
    if (outc) { outc[o + l] = v0; outc[o + 64 + l] = v1; }
    else      { outr[o + l] = v0.x; outr[o + 64 + l] = v1.x; }

    X[0] = v0; X[1] = v1;
#pragma unroll
    for (int k = 2; k < 8; ++k) X[k] = make_float2(0.f, 0.f);
    fwd512(X, ex, l, make_float2(b1.x, -b1.y), make_float2(b2.x, -b2.y));
#pragma unroll
    for (int d = 0; d < 8; ++d) arow[l + 64*d] = X[d];
}

// ---------------------------------------------------------------------------
// pass D last: row IFFT + crop + output + |.|^2. No barriers.
// ---------------------------------------------------------------------------
__global__ __launch_bounds__(256) void k_passDlast(const float2* __restrict__ Abuf,
                                                   float2* __restrict__ outc,
                                                   float*  __restrict__ outr,
                                                   float*  __restrict__ outabs)
{
    __shared__ float2 ex_all[4*EXSZ];
    const int w = threadIdx.x >> 6, l = threadIdx.x & 63;
    const int row = blockIdx.x*4 + w, img = blockIdx.y;
    float2* ex = ex_all + w*EXSZ;
    float2 b1, b2;
    make_bases(l, &b1, &b2);

    const float2* arow = Abuf + (size_t)(img*NPIX + row)*NFFT;
    float2 X[8];
#pragma unroll
    for (int d = 0; d < 8; ++d) X[d] = arow[l + 64*d];
    inv512(X, ex, l, b1, b2);

    float2 v0 = X[2], v1 = X[3];
    size_t o = (size_t)(img*NPIX + row)*NPIX;
    if (outc) { outc[o + l] = v0; outc[o + 64 + l] = v1; }
    else      { outr[o + l] = v0.x; outr[o + 64 + l] = v1.x; }
    outabs[o + l]      = v0.x*v0.x + v0.y*v0.y;
    outabs[o + 64 + l] = v1.x*v1.x + v1.y*v1.y;
}

// ---------------------------------------------------------------------------
extern "C" void kernel_launch(void* const* d_in, const int* in_sizes, int n_in,
                              void* d_out, int out_size, void* d_ws, size_t ws_size,
                              hipStream_t stream)
{
    const float* x      = (const float*)d_in[0];   // [64,128,128]
    const float* phases = (const float*)d_in[1];   // [5,64,64]
    float* out = (float*)d_out;
    char*  ws  = (char*)d_ws;

    // workspace layout
    float2* Ht   = (float2*)ws;                                   // 2 MB
    float2* Abuf = (float2*)(ws + (size_t)NFFT*NFFT*8);           // 33.5 MB
    // double temporaries for H construction alias the (not-yet-used) Abuf
    double2* Wd = (double2*)Abuf;                                 // 4 MB
    double2* Td = (double2*)((char*)Abuf + (size_t)NFFT*NFFT*16); // 4 MB

    const bool   inter   = (out_size >= 15728640);
    const size_t cstride = inter ? 2097152u : 1048576u;

    k_build_w   <<<1024, 256, 0, stream>>>(Wd);
    k_dfft_row  <<<NFFT, 256, 0, stream>>>(Wd, Td);
    k_dfft_col_H<<<NFFT, 256, 0, stream>>>(Td, Ht);

    {
        float* c1 = out + 1048576;
        k_passA0<<<dim3(NPIX/4, BATCH), 256, 0, stream>>>(
            x, Abuf,
            inter ? (float2*)c1 : nullptr,
            inter ? nullptr : c1);
    }

    for (int step = 0; step < 6; ++step) {
        k_passBC<<<dim3(BATCH, NFFT/8), 512, 0, stream>>>(Abuf, Ht);
        float* chunk = out + 1048576 + (size_t)(step + 1)*cstride;
        if (step < 5) {
            k_passDA<<<dim3(NPIX/4, BATCH), 256, 0, stream>>>(
                Abuf, phases,
                inter ? (float2*)chunk : nullptr,
                inter ? nullptr : chunk, step);
        } else {
            k_passDlast<<<dim3(NPIX/4, BATCH), 256, 0, stream>>>(
                Abuf,
                inter ? (float2*)chunk : nullptr,
                inter ? nullptr : chunk,
                out /* x_abs chunk0 */);
        }
    }
}

// Round 8
// 431.626 us; speedup vs baseline: 1.0840x; 1.0840x over previous
//
#include <hip/hip_runtime.h>
#include <math.h>

#define PI_D 3.14159265358979323846264338327950288
#define C707 0.70710678118654752440f

#define NPIX 128
#define NFFT 512
#define BATCH 64
#define EXSZ 512          // per-wave exchange region (v2f), XOR layout, no pad
#define TSTR 130          // passBC staging tile column stride (v2f)

// two-float vector type: backend forms v_pk_*_f32 where legal
typedef float v2f __attribute__((ext_vector_type(2)));

// Compiler-only reorder barrier: intra-wave LDS RAW/WAR needs no s_waitcnt
// (DS ops from one wave execute in order; compiler inserts fine-grained
// lgkmcnt before dependent VALU use).
#define CBAR() __asm__ volatile("" ::: "memory")

// ---------------------------------------------------------------------------
// complex primitives on v2f (compiler-chosen packed encodings)
// ---------------------------------------------------------------------------
__device__ __forceinline__ v2f cmul(v2f a, v2f b) {
    v2f c; c.x = -b.y; c.y = b.x;        // i*b
    return a.xx * b + a.yy * c;          // a.x*b + a.y*(i*b)
}
__device__ __forceinline__ v2f conjv(v2f a) {
    v2f r; r.x = a.x; r.y = -a.y; return r;
}
// SGN*i*a
template<int SGN> __device__ __forceinline__ v2f muli(v2f a) {
    v2f r;
    if (SGN > 0) { r.x = -a.y; r.y =  a.x; }
    else         { r.x =  a.y; r.y = -a.x; }
    return r;
}

// conflict-free exchange address maps (bijective mod 16 per 16-lane group)
__device__ __forceinline__ int ex1w(int k, int l)           { return 64*k  + (l ^ (2*k)); }
__device__ __forceinline__ int ex1r(int k, int k2, int hi)  { return 64*k2 + ((hi + 8*k) ^ (2*k2)); }
__device__ __forceinline__ int ex2w(int k, int l)           { return 64*k  + (l ^ (8*k)); }
__device__ __forceinline__ int ex2r(int k, int k2, int hi)  { return 64*hi + ((k2 + 8*k) ^ (8*hi)); }

// ---------------------------------------------------------------------------
// in-register 8-point DFT. SGN=-1 forward; SGN=+1 unnormalized inverse.
// u5 = C*(t5 + SGN*i*t5); u6 = SGN*i*t6; u7 = C*(SGN*i*t7 - t7)
// ---------------------------------------------------------------------------
template<int SGN>
__device__ __forceinline__ void dft8(v2f* x)
{
    v2f t0 = x[0] + x[4], t4 = x[0] - x[4];
    v2f t1 = x[1] + x[5], t5 = x[1] - x[5];
    v2f t2 = x[2] + x[6], t6 = x[2] - x[6];
    v2f t3 = x[3] + x[7], t7 = x[3] - x[7];
    v2f u5 = C707 * (t5 + muli<SGN>(t5));
    v2f u6 = muli<SGN>(t6);
    v2f u7 = C707 * (muli<SGN>(t7) - t7);
    v2f s0 = t0 + t2, s2 = t0 - t2;
    v2f s1 = t1 + t3, d13 = t1 - t3;
    v2f s3 = muli<SGN>(d13);
    x[0] = s0 + s1; x[4] = s0 - s1;
    x[2] = s2 + s3; x[6] = s2 - s3;
    v2f s4 = t4 + u6, s6 = t4 - u6;
    v2f s5 = u5 + u7, d57 = u5 - u7;
    v2f s7 = muli<SGN>(d57);
    x[1] = s4 + s5; x[5] = s4 - s5;
    x[3] = s6 + s7; x[7] = s6 - s7;
}

// forward first stage specialized for inputs (a,b,0,0,0,0,0,0):
// x[k] = a + b*w8^k  (w8 = exp(-2pi i/8))
__device__ __forceinline__ void dft8_f2(v2f* x)
{
    v2f a = x[0], b = x[1];
    v2f bw1 = C707 * (b + muli<-1>(b));   // b*w8
    v2f bw2 = muli<-1>(b);                // b*w8^2
    v2f bw3 = muli<-1>(bw1);              // b*w8^3
    x[0] = a + b;   x[4] = a - b;
    x[1] = a + bw1; x[5] = a - bw1;
    x[2] = a + bw2; x[6] = a - bw2;
    x[3] = a + bw3; x[7] = a - bw3;
}

// inverse (SGN=+1) last stage computing only outputs 2 and 3 (cropped window)
__device__ __forceinline__ void dft8_i23(const v2f* x, v2f* o2, v2f* o3)
{
    v2f t0 = x[0] + x[4], t4 = x[0] - x[4];
    v2f t1 = x[1] + x[5], t5 = x[1] - x[5];
    v2f t2 = x[2] + x[6], t6 = x[2] - x[6];
    v2f t3 = x[3] + x[7], t7 = x[3] - x[7];
    v2f s2  = t0 - t2;
    v2f d13 = t1 - t3;
    *o2 = s2 + muli<1>(d13);
    v2f u5 = C707 * (t5 + muli<1>(t5));
    v2f u6 = muli<1>(t6);
    v2f u7 = C707 * (muli<1>(t7) - t7);
    v2f s6  = t4 - u6;
    v2f d57 = u5 - u7;
    *o3 = s6 + muli<1>(d57);
}

// apply x[k] *= base^k for k=1..7 (6-extra-cmul chain, low VGPR)
__device__ __forceinline__ void twpow(v2f* x, v2f base)
{
    v2f w = base;
    x[1] = cmul(x[1], w);
#pragma unroll
    for (int k = 2; k < 8; ++k) {
        w = cmul(w, base);
        x[k] = cmul(x[k], w);
    }
}

// per-lane twiddle bases (positive angle): b1 = w512^l, b2 = w64^{l>>3}
__device__ __forceinline__ void make_bases(int l, v2f* b1, v2f* b2)
{
    float s1, c1, s2, c2;
    __sincosf(0.012271846303085129838f * (float)l,        &s1, &c1); // 2pi/512
    __sincosf(0.098174770424681038701f * (float)(l >> 3), &s2, &c2); // 2pi/64
    b1->x = c1; b1->y = s1;
    b2->x = c2; b2->y = s2;
}

// ---------------------------------------------------------------------------
// 512-pt FFT, one wave, 8 complex/lane, radix-8 x3, natural order both ends.
// fwd512: inputs only in x[0],x[1] (zero-pad pruned).
// inv512_crop: only outputs 2,3 of the final stage (crop pruned).
// bases passed with FORWARD sign already applied (conj at callsite for fwd).
// ---------------------------------------------------------------------------
__device__ __forceinline__ void fwd512(v2f* x, v2f* ex, int l, v2f b1, v2f b2)
{
    const int k2 = l & 7, hi = l >> 3;
    dft8_f2(x);
    twpow(x, b1);
    CBAR();
#pragma unroll
    for (int k = 0; k < 8; ++k) ex[ex1w(k, l)] = x[k];
    CBAR();
#pragma unroll
    for (int k = 0; k < 8; ++k) x[k] = ex[ex1r(k, k2, hi)];
    dft8<-1>(x);
    twpow(x, b2);
    CBAR();
#pragma unroll
    for (int k = 0; k < 8; ++k) ex[ex2w(k, l)] = x[k];
    CBAR();
#pragma unroll
    for (int k = 0; k < 8; ++k) x[k] = ex[ex2r(k, k2, hi)];
    dft8<-1>(x);
}

__device__ __forceinline__ void inv512_crop(v2f* x, v2f* ex, int l,
                                            v2f b1, v2f b2, v2f* o2, v2f* o3)
{
    const int k2 = l & 7, hi = l >> 3;
    dft8<1>(x);
    CBAR();
#pragma unroll
    for (int k = 0; k < 8; ++k) ex[ex2r(k, k2, hi)] = x[k];
    CBAR();
#pragma unroll
    for (int k = 0; k < 8; ++k) x[k] = ex[ex2w(k, l)];
    twpow(x, b2);
    dft8<1>(x);
    CBAR();
#pragma unroll
    for (int k = 0; k < 8; ++k) ex[ex1r(k, k2, hi)] = x[k];
    CBAR();
#pragma unroll
    for (int k = 0; k < 8; ++k) x[k] = ex[ex1w(k, l)];
    twpow(x, b1);
    dft8_i23(x, o2, o3);
}

// ---------------------------------------------------------------------------
// setup: H built in double precision (table-driven twiddles)
// ---------------------------------------------------------------------------
__global__ __launch_bounds__(256) void k_dtw(double2* __restrict__ dtw)
{
    int t = threadIdx.x;             // 256: w512^t = exp(-i*pi*t/256)
    double s, c;
    sincos(-PI_D/256.0 * (double)t, &s, &c);
    dtw[t] = make_double2(c, s);
}

__device__ __forceinline__ int fft512d(double2 (*b)[NFFT], int t, int cur,
                                       const double2* __restrict__ tw)
{
    for (int st = 0; st < 9; ++st) {
        const int s = 1 << st;
        const int p = t >> st;
        const int q = t & (s - 1);
        const int m = 256 >> st;
        const double2 a = b[cur][q + s*p];
        const double2 c = b[cur][q + s*(p + m)];
        const double2 wv = tw[p << st];
        const double2 dif = make_double2(a.x - c.x, a.y - c.y);
        b[cur^1][q + 2*s*p]     = make_double2(a.x + c.x, a.y + c.y);
        b[cur^1][q + 2*s*p + s] = make_double2(dif.x*wv.x - dif.y*wv.y,
                                               dif.x*wv.y + dif.y*wv.x);
        cur ^= 1;
        __syncthreads();
    }
    return cur;
}

__global__ __launch_bounds__(256) void k_build_w(double2* __restrict__ Wd)
{
    const double WLEN = 5.32e-07, PIX = 1.0e-4, DIST = 0.005;
    int idx = blockIdx.x*blockDim.x + threadIdx.x;   // 512*512 total
    int i = idx >> 9, j = idx & 511;
    double2 v = make_double2(0.0, 0.0);
    if (i < 257 && j < 257) {
        double cx = (double)(128 - i) * PIX;
        double cy = (double)(128 - j) * PIX;
        double r2 = cx*cx + cy*cy + DIST*DIST;
        double r  = sqrt(r2);
        double sc = PIX*PIX*DIST / r2;
        double re_a = 1.0/(2.0*PI_D*r);
        double im_a = -1.0/WLEN;
        double sp, cp;
        sincos(2.0*PI_D*r/WLEN, &sp, &cp);
        v.x = sc*(re_a*cp - im_a*sp);
        v.y = sc*(re_a*sp + im_a*cp);
    }
    Wd[idx] = v;
}

__global__ __launch_bounds__(256) void k_dfft_row(const double2* __restrict__ in,
                                                  double2* __restrict__ out,
                                                  const double2* __restrict__ tw)
{
    __shared__ double2 b[2][NFFT];
    int row = blockIdx.x, t = threadIdx.x;
    b[0][t]       = in[row*NFFT + t];
    b[0][t + 256] = in[row*NFFT + t + 256];
    __syncthreads();
    int cur = fft512d(b, t, 0, tw);
    out[row*NFFT + t]       = b[cur][t];
    out[row*NFFT + t + 256] = b[cur][t + 256];
}

// column FFT; Ht[kx*512 + ky] natural order, 1/512^2 folded in.
__global__ __launch_bounds__(256) void k_dfft_col_H(const double2* __restrict__ in,
                                                    float2* __restrict__ Ht,
                                                    const double2* __restrict__ tw)
{
    __shared__ double2 b[2][NFFT];
    int col = blockIdx.x, t = threadIdx.x;
    b[0][t]       = in[t*NFFT + col];
    b[0][t + 256] = in[(t + 256)*NFFT + col];
    __syncthreads();
    int cur = fft512d(b, t, 0, tw);
    const double scale = 1.0/(512.0*512.0);
    Ht[col*NFFT + t]       = make_float2((float)(b[cur][t].x*scale),
                                         (float)(b[cur][t].y*scale));
    Ht[col*NFFT + t + 256] = make_float2((float)(b[cur][t+256].x*scale),
                                         (float)(b[cur][t+256].y*scale));
}

// ---------------------------------------------------------------------------
// pass A0: init + first row FFT. block 256 = 4 waves = 4 rows, no barriers.
// ---------------------------------------------------------------------------
__global__ __launch_bounds__(256, 8) void k_passA0(const float* __restrict__ x,
                                                   v2f* __restrict__ Abuf,
                                                   v2f* __restrict__ outc,
                                                   float* __restrict__ outr)
{
    __shared__ v2f ex_all[4*EXSZ];
    const int w = threadIdx.x >> 6, l = threadIdx.x & 63;
    const int row = blockIdx.x*4 + w, img = blockIdx.y;
    v2f* ex = ex_all + w*EXSZ;
    v2f b1, b2;
    make_bases(l, &b1, &b2);

    const float* xr = x + (size_t)(img*NPIX + row)*NPIX;
    v2f v0; v0.x = xr[l];      v0.y = 0.f;
    v2f v1; v1.x = xr[l + 64]; v1.y = 0.f;
    size_t o = (size_t)(img*NPIX + row)*NPIX;
    if (outc) { outc[o + l] = v0; outc[o + 64 + l] = v1; }
    else      { outr[o + l] = v0.x; outr[o + 64 + l] = v1.x; }

    v2f X[8];
    X[0] = v0; X[1] = v1;
    fwd512(X, ex, l, conjv(b1), conjv(b2));
    v2f* arow = Abuf + (size_t)(img*NPIX + row)*NFFT;
#pragma unroll
    for (int d = 0; d < 8; ++d) arow[l + 64*d] = X[d];
}

// ---------------------------------------------------------------------------
// pass BC: 8 columns/block (512 thr = 8 waves, 1 col each). Staging tile T
// aliases the exchange region (disjoint lifetimes). LDS 32 KB.
// ---------------------------------------------------------------------------
__global__ __launch_bounds__(512, 8) void k_passBC(v2f* __restrict__ Abuf,
                                                   const v2f* __restrict__ Ht)
{
    __shared__ v2f ex_all[8*EXSZ];   // 32768 B: exchange + aliased staging
    v2f* T = ex_all;                 // staging tile: 8*TSTR = 1040 slots
    const int t = threadIdx.x;
    const int w = t >> 6, l = t & 63;
    const int img = blockIdx.x, c0 = blockIdx.y*8;
    v2f* base = Abuf + (size_t)img*NPIX*NFFT;
    v2f b1, b2;
    make_bases(l, &b1, &b2);

    // coalesced tile load: (128 rows x 8 cols)
#pragma unroll
    for (int i = 0; i < 2; ++i) {
        int idx = t + 512*i;
        int cc = idx & 7, r = idx >> 3;
        T[cc*TSTR + r] = base[r*NFFT + c0 + cc];
    }
    __syncthreads();

    v2f* ex = ex_all + w*EXSZ;
    v2f X[8];
    X[0] = T[w*TSTR + l];
    X[1] = T[w*TSTR + l + 64];
    __syncthreads();   // all waves read T before exchanges overwrite it

    fwd512(X, ex, l, conjv(b1), conjv(b2));
    const v2f* Hrow = Ht + (size_t)(c0 + w)*NFFT;
#pragma unroll
    for (int d = 0; d < 8; ++d) X[d] = cmul(X[d], Hrow[l + 64*d]);
    v2f y2, y3;
    inv512_crop(X, ex, l, b1, b2, &y2, &y3);

    __syncthreads();   // all waves done with exchange regions
    // keep spatial rows 128..255 (cropped outputs)
    T[w*TSTR + l]      = y2;
    T[w*TSTR + l + 64] = y3;
    __syncthreads();

#pragma unroll
    for (int i = 0; i < 2; ++i) {
        int idx = t + 512*i;
        int cc = idx & 7, r = idx >> 3;
        base[r*NFFT + c0 + cc] = T[cc*TSTR + r];
    }
}

// ---------------------------------------------------------------------------
// pass DA: row IFFT + crop + mask + output, then forward row FFT. No barriers.
// ---------------------------------------------------------------------------
__global__ __launch_bounds__(256, 8) void k_passDA(v2f* __restrict__ Abuf,
                                                   const float* __restrict__ phases,
                                                   v2f* __restrict__ outc,
                                                   float* __restrict__ outr,
                                                   int layer)
{
    __shared__ v2f ex_all[4*EXSZ];
    const int w = threadIdx.x >> 6, l = threadIdx.x & 63;
    const int row = blockIdx.x*4 + w, img = blockIdx.y;
    v2f* ex = ex_all + w*EXSZ;
    v2f b1, b2;
    make_bases(l, &b1, &b2);

    v2f* arow = Abuf + (size_t)(img*NPIX + row)*NFFT;
    v2f X[8];
#pragma unroll
    for (int d = 0; d < 8; ++d) X[d] = arow[l + 64*d];
    v2f y2, y3;
    inv512_crop(X, ex, l, b1, b2, &y2, &y3);

    // crop cols 128..255 -> j=l (y2), j=64+l (y3); apply phase mask
    const float* ph = phases + layer*4096 + (row >> 1)*64;
    float p0 = ph[(l >> 1)];
    float p1 = ph[32 + (l >> 1)];
    float cp0 = 6.2831853071795864769f * (1.f/(1.f + __expf(-p0)));
    float cp1 = 6.2831853071795864769f * (1.f/(1.f + __expf(-p1)));
    float s0, c0s, s1, c1s;
    __sincosf(cp0, &s0, &c0s);
    __sincosf(cp1, &s1, &c1s);
    v2f m0; m0.x = c0s; m0.y = s0;
    v2f m1; m1.x = c1s; m1.y = s1;
    v2f v0 = cmul(y2, m0);
    v2f v1 = cmul(y3, m1);

    size_t o = (size_t)(img*NPIX + row)*NPIX;
    if (outc) { outc[o + l] = v0; outc[o + 64 + l] = v1; }
    else      { outr[o + l] = v0.x; outr[o + 64 + l] = v1.x; }

    X[0] = v0; X[1] = v1;
    fwd512(X, ex, l, conjv(b1), conjv(b2));
#pragma unroll
    for (int d = 0; d < 8; ++d) arow[l + 64*d] = X[d];
}

// ---------------------------------------------------------------------------
// pass D last: row IFFT + crop + output + |.|^2. No barriers.
// ---------------------------------------------------------------------------
__global__ __launch_bounds__(256, 8) void k_passDlast(const v2f* __restrict__ Abuf,
                                                      v2f* __restrict__ outc,
                                                      float* __restrict__ outr,
                                                      float* __restrict__ outabs)
{
    __shared__ v2f ex_all[4*EXSZ];
    const int w = threadIdx.x >> 6, l = threadIdx.x & 63;
    const int row = blockIdx.x*4 + w, img = blockIdx.y;
    v2f* ex = ex_all + w*EXSZ;
    v2f b1, b2;
    make_bases(l, &b1, &b2);

    const v2f* arow = Abuf + (size_t)(img*NPIX + row)*NFFT;
    v2f X[8];
#pragma unroll
    for (int d = 0; d < 8; ++d) X[d] = arow[l + 64*d];
    v2f v0, v1;
    inv512_crop(X, ex, l, b1, b2, &v0, &v1);

    size_t o = (size_t)(img*NPIX + row)*NPIX;
    if (outc) { outc[o + l] = v0; outc[o + 64 + l] = v1; }
    else      { outr[o + l] = v0.x; outr[o + 64 + l] = v1.x; }
    outabs[o + l]      = v0.x*v0.x + v0.y*v0.y;
    outabs[o + 64 + l] = v1.x*v1.x + v1.y*v1.y;
}

// ---------------------------------------------------------------------------
extern "C" void kernel_launch(void* const* d_in, const int* in_sizes, int n_in,
                              void* d_out, int out_size, void* d_ws, size_t ws_size,
                              hipStream_t stream)
{
    const float* x      = (const float*)d_in[0];   // [64,128,128]
    const float* phases = (const float*)d_in[1];   // [5,64,64]
    float* out = (float*)d_out;
    char*  ws  = (char*)d_ws;

    // workspace layout
    float2*  HtF  = (float2*)ws;                                     // 2 MB
    double2* dtw  = (double2*)(ws + (size_t)NFFT*NFFT*8);            // 4 KB
    v2f*     Abuf = (v2f*)(ws + (size_t)NFFT*NFFT*8 + 4096);        // 33.5 MB
    // double temporaries for H construction alias the (not-yet-used) Abuf
    double2* Wd = (double2*)Abuf;                                    // 4 MB
    double2* Td = (double2*)((char*)Abuf + (size_t)NFFT*NFFT*16);    // 4 MB

    const bool   inter   = (out_size >= 15728640);
    const size_t cstride = inter ? 2097152u : 1048576u;

    k_dtw       <<<1,    256, 0, stream>>>(dtw);
    k_build_w   <<<1024, 256, 0, stream>>>(Wd);
    k_dfft_row  <<<NFFT, 256, 0, stream>>>(Wd, Td, dtw);
    k_dfft_col_H<<<NFFT, 256, 0, stream>>>(Td, HtF, dtw);

    {
        float* c1 = out + 1048576;
        k_passA0<<<dim3(NPIX/4, BATCH), 256, 0, stream>>>(
            x, Abuf,
            inter ? (v2f*)c1 : nullptr,
            inter ? nullptr : c1);
    }

    for (int step = 0; step < 6; ++step) {
        k_passBC<<<dim3(BATCH, NFFT/8), 512, 0, stream>>>(Abuf, (const v2f*)HtF);
        float* chunk = out + 1048576 + (size_t)(step + 1)*cstride;
        if (step < 5) {
            k_passDA<<<dim3(NPIX/4, BATCH), 256, 0, stream>>>(
                Abuf, phases,
                inter ? (v2f*)chunk : nullptr,
                inter ? nullptr : chunk, step);
        } else {
            k_passDlast<<<dim3(NPIX/4, BATCH), 256, 0, stream>>>(
                Abuf,
                inter ? (v2f*)chunk : nullptr,
                inter ? nullptr : chunk,
                out /* x_abs chunk0 */);
        }
    }
}